// Round 5
// baseline (347.121 us; speedup 1.0000x reference)
//
#include <hip/hip_runtime.h>
#include <hip/hip_bf16.h>

#define D 128
#define EPS 1e-5f
#define CHK 8192            // edges per phase-1 chunk
#define P2CAP 6144          // max edges per 256-dst bucket

typedef __attribute__((ext_vector_type(8))) short short8;
typedef __attribute__((ext_vector_type(4))) float float4v;

#define AS1 __attribute__((address_space(1)))
#define AS3 __attribute__((address_space(3)))

__device__ inline ushort f2bf(float f) {
    __hip_bfloat16 b = __float2bfloat16(f);
    return *reinterpret_cast<ushort*>(&b);
}
__device__ inline float bf_lo(uint u) { return __uint_as_float(u << 16); }
__device__ inline float bf_hi(uint u) { return __uint_as_float(u & 0xffff0000u); }

// ---------- K1: fused weight-convert (blocks 0..12) + LN1+ReLU (rest) ---------
// cvt: m==0 W_root, 1..8 W_rel[m-1], 9..12 W_mlp[m-9] -> bf16 B-fragment order.
__global__ void k_ln1cvt(const float* __restrict__ x, const int* __restrict__ ntp,
                         const float* __restrict__ gamma, const float* __restrict__ beta,
                         ushort* __restrict__ y,
                         const float* __restrict__ Wrel, const float* __restrict__ Wroot,
                         const float* __restrict__ Wmlp, ushort* __restrict__ Wt, int N) {
    __shared__ ushort t[128][136];
    if (blockIdx.x < 13) {
        int m = blockIdx.x;
        const float* src = (m == 0) ? Wroot
                         : (m <= 8) ? Wrel + (size_t)(m - 1) * D * D
                                    : Wmlp + (size_t)(m - 9) * D * D;
        for (int i = threadIdx.x; i < D * D; i += 256) {
            int k = i >> 7, n = i & 127;
            t[n][k] = f2bf(src[i]);
        }
        __syncthreads();
        ushort* dst = Wt + (size_t)m * D * D;
        for (int i = threadIdx.x; i < D * D; i += 256) {
            int frag = i >> 9;
            int lane = (i >> 3) & 63;
            int j = i & 7;
            int nt = frag >> 2, ks = frag & 3;
            int n = nt * 16 + (lane & 15);
            int k = ks * 32 + (lane >> 4) * 8 + j;
            dst[i] = t[n][k];
        }
        return;
    }
    int n = (blockIdx.x - 13) * 4 + (threadIdx.x >> 6);
    if (n >= N) return;
    int l = threadIdx.x & 63;
    float2 v = *(const float2*)(x + (size_t)n * D + 2 * l);
    float s = v.x + v.y, s2 = v.x * v.x + v.y * v.y;
    #pragma unroll
    for (int o = 32; o; o >>= 1) { s += __shfl_xor(s, o, 64); s2 += __shfl_xor(s2, o, 64); }
    float mu = s * (1.0f / D);
    float var = s2 * (1.0f / D) - mu * mu;
    float inv = rsqrtf(var + EPS);
    int tt = ntp[n];
    float2 g = *(const float2*)(gamma + tt * D + 2 * l);
    float2 b = *(const float2*)(beta + tt * D + 2 * l);
    float a0 = fmaxf((v.x - mu) * inv * g.x + b.x, 0.0f);
    float a1 = fmaxf((v.y - mu) * inv * g.y + b.y, 0.0f);
    ((uint*)(y + (size_t)n * D))[l] = ((uint)f2bf(a1) << 16) | f2bf(a0);
}

// ---------- two-phase edge sort by dst (block-owned write regions) ------------
__global__ void k_c1(const int* __restrict__ edst, int* __restrict__ hist, int E, int B) {
    __shared__ int cnt[256];
    int c = blockIdx.x, tid = threadIdx.x;
    cnt[tid] = 0;
    __syncthreads();
    #pragma unroll 4
    for (int k = 0; k < CHK / 256; ++k) {
        int e = c * CHK + k * 256 + tid;
        if (e < E) atomicAdd(&cnt[edst[e] >> 8], 1);
    }
    __syncthreads();
    if (tid < B) hist[c * B + tid] = cnt[tid];
}
__global__ void k_c2(const int* __restrict__ hist, int* __restrict__ chunkoff,
                     int* __restrict__ bucktot, int C, int B) {
    __shared__ int v[128];
    int b = blockIdx.x, t = threadIdx.x;
    v[t] = (t < C) ? hist[t * B + b] : 0;
    __syncthreads();
    if (t == 0) {
        int s = 0;
        for (int c = 0; c < C; ++c) { int x = v[c]; v[c] = s; s += x; }
        bucktot[b] = s;
    }
    __syncthreads();
    if (t < C) chunkoff[t * B + b] = v[t];
}
// p1s: scatter edges into bucket-major edata; in-block scan of bucktot -> base
__global__ void k_p1s(const int* __restrict__ edst, const int* __restrict__ esrc,
                      const int* __restrict__ etyp, const int* __restrict__ bucktot,
                      const int* __restrict__ chunkoff, uint* __restrict__ edata,
                      int E, int B) {
    __shared__ int ps[256];
    __shared__ int base[256];
    __shared__ int cnt[256];
    int c = blockIdx.x, tid = threadIdx.x;
    int bt = (tid < B) ? bucktot[tid] : 0;
    ps[tid] = bt;
    __syncthreads();
    for (int o = 1; o < 256; o <<= 1) {
        int v = (tid >= o) ? ps[tid - o] : 0;
        __syncthreads();
        ps[tid] += v;
        __syncthreads();
    }
    base[tid] = (ps[tid] - bt) + ((tid < B) ? chunkoff[c * B + tid] : 0);
    cnt[tid] = 0;
    __syncthreads();
    #pragma unroll 4
    for (int k = 0; k < CHK / 256; ++k) {
        int e = c * CHK + k * 256 + tid;
        if (e < E) {
            int d = edst[e];
            int b = d >> 8;
            int r = atomicAdd(&cnt[b], 1);
            edata[base[b] + r] =
                ((uint)esrc[e] << 12) | ((uint)(d & 255) << 4) | (uint)etyp[e];
        }
    }
}
// p2: exact counting-sort within each 256-dst bucket; in-block scan for j0
__global__ void k_p2(const uint* __restrict__ edata, const int* __restrict__ bucktot,
                     uint* __restrict__ epack, int* __restrict__ offs,
                     int N, int E, int B) {
    __shared__ int ps[256];
    __shared__ uint ed[P2CAP];
    __shared__ int cnt[256], off[256], cur[256];
    int b = blockIdx.x, tid = threadIdx.x;
    int bt = (tid < B) ? bucktot[tid] : 0;
    ps[tid] = bt;
    __syncthreads();
    for (int o = 1; o < 256; o <<= 1) {
        int v = (tid >= o) ? ps[tid - o] : 0;
        __syncthreads();
        ps[tid] += v;
        __syncthreads();
    }
    int j0 = ps[b] - ((b < B) ? bucktot[b] : 0);   // exclusive prefix of bucket b
    int count = ps[b] - j0;
    if (count > P2CAP) count = P2CAP;
    for (int i = tid; i < count; i += 256) ed[i] = edata[j0 + i];
    cnt[tid] = 0;
    __syncthreads();
    for (int i = tid; i < count; i += 256) atomicAdd(&cnt[(ed[i] >> 4) & 255], 1);
    __syncthreads();
    if (tid == 0) {
        int s = 0;
        for (int i = 0; i < 256; ++i) { off[i] = s; cur[i] = s; s += cnt[i]; }
    }
    __syncthreads();
    for (int i = tid; i < count; i += 256) {
        uint v = ed[i];
        int dl = (v >> 4) & 255;
        int r = atomicAdd(&cur[dl], 1);
        epack[j0 + r] = ((v & 15u) << 28) | (v >> 12);
    }
    int v = b * 256 + tid;
    if (v < N) offs[v] = j0 + off[tid];
    if (b == 0 && tid == 0) offs[N] = E;
}

// ---------- K3: z[v][r] = sum of y[src] over edges (dst=v, type=r) ------------
__global__ void k_zagg(const ushort* __restrict__ ybuf, const int* __restrict__ offs,
                       const uint* __restrict__ epack, ushort* __restrict__ zbuf, int N) {
    int wave = threadIdx.x >> 6;
    int l = threadIdx.x & 63;
    int v = blockIdx.x * 4 + wave;
    if (v >= N) return;
    float2 a0 = {0.f,0.f}, a1 = {0.f,0.f}, a2 = {0.f,0.f}, a3 = {0.f,0.f};
    float2 a4 = {0.f,0.f}, a5 = {0.f,0.f}, a6 = {0.f,0.f}, a7 = {0.f,0.f};
    const uint* yb = (const uint*)ybuf;
    int j = offs[v], e1 = offs[v + 1];

#define ZACC(P, U) do {                                                   \
        float lo = bf_lo(U), hi = bf_hi(U);                               \
        switch ((P) >> 28) {                                              \
            case 0: a0.x += lo; a0.y += hi; break;                        \
            case 1: a1.x += lo; a1.y += hi; break;                        \
            case 2: a2.x += lo; a2.y += hi; break;                        \
            case 3: a3.x += lo; a3.y += hi; break;                        \
            case 4: a4.x += lo; a4.y += hi; break;                        \
            case 5: a5.x += lo; a5.y += hi; break;                        \
            case 6: a6.x += lo; a6.y += hi; break;                        \
            default: a7.x += lo; a7.y += hi; break;                       \
        }                                                                 \
    } while (0)

    while (j < e1) {
        int chunk = min(64, e1 - j);
        uint pl = (j + l < e1) ? epack[j + l] : 0;
        int i = 0;
        for (; i + 3 < chunk; i += 4) {
            uint p0 = __shfl(pl, i, 64);
            uint p1 = __shfl(pl, i + 1, 64);
            uint p2 = __shfl(pl, i + 2, 64);
            uint p3 = __shfl(pl, i + 3, 64);
            uint u0 = yb[(size_t)(p0 & 0x0FFFFFFFu) * 64 + l];
            uint u1 = yb[(size_t)(p1 & 0x0FFFFFFFu) * 64 + l];
            uint u2 = yb[(size_t)(p2 & 0x0FFFFFFFu) * 64 + l];
            uint u3 = yb[(size_t)(p3 & 0x0FFFFFFFu) * 64 + l];
            ZACC(p0, u0); ZACC(p1, u1); ZACC(p2, u2); ZACC(p3, u3);
        }
        for (; i < chunk; ++i) {
            uint p = __shfl(pl, i, 64);
            uint u = yb[(size_t)(p & 0x0FFFFFFFu) * 64 + l];
            ZACC(p, u);
        }
        j += chunk;
    }
#undef ZACC
    uint* zrow = (uint*)(zbuf + (size_t)v * 1024);
    zrow[0 * 64 + l] = ((uint)f2bf(a0.y) << 16) | f2bf(a0.x);
    zrow[1 * 64 + l] = ((uint)f2bf(a1.y) << 16) | f2bf(a1.x);
    zrow[2 * 64 + l] = ((uint)f2bf(a2.y) << 16) | f2bf(a2.x);
    zrow[3 * 64 + l] = ((uint)f2bf(a3.y) << 16) | f2bf(a3.x);
    zrow[4 * 64 + l] = ((uint)f2bf(a4.y) << 16) | f2bf(a4.x);
    zrow[5 * 64 + l] = ((uint)f2bf(a5.y) << 16) | f2bf(a5.x);
    zrow[6 * 64 + l] = ((uint)f2bf(a6.y) << 16) | f2bf(a6.x);
    zrow[7 * 64 + l] = ((uint)f2bf(a7.y) << 16) | f2bf(a7.x);
}

// ---------- K4: LDS-staged conv-GEMM (K=1152) + LN2 + ReLU + MLP --------------
// B-operand bandwidth fix: each of the 13 weight mats is staged ONCE per block
// into LDS via global_load_lds, in 16KB half-mat ping-pong phases, shared by
// all 4 waves (4x less L2 B-traffic than per-wave global reads).
// R5: SAFE SYNC VARIANT. R3/R4's raw s_barrier + hand-counted vmcnt produced a
// residual numerical error that survived two full audits -> suspect compiler
// code motion across bare s_barrier. All phase boundaries are now plain
// __syncthreads() (compiler emits s_waitcnt vmcnt(0) lgkmcnt(0) + s_barrier:
// guaranteed stage/ds ordering). A-prefetch kept: issued one phase before use
// (R4 ordering: convHalf consumes cur BEFORE aload4 overwrites it); its
// latency overlaps the phase's MFMAs and drains with the same barrier wait.
__device__ __forceinline__ void gl_lds16(const void* g, void* l) {
    __builtin_amdgcn_global_load_lds((const AS1 void*)g, (AS3 void*)l, 16, 0, 0);
}
// stage 16KB half q (Wt bytes [q*16384, +16384)) into bsm[q&1]; 4KB per wave
__device__ __forceinline__ void stage_half(const ushort* __restrict__ Wt, int q,
                                           ushort* bsm0, int wave, int lane) {
    const char* g = (const char*)Wt + (size_t)q * 16384 + lane * 16;
    char* l = (char*)bsm0 + (q & 1) * 16384;
    #pragma unroll
    for (int i = 0; i < 4; ++i) {
        int c = i * 4 + wave;
        gl_lds16(g + c * 1024, l + c * 1024);
    }
}
__device__ __forceinline__ void aload4(short8 (&d)[2][4], const ushort* p0,
                                       const ushort* p1, int off, int ao) {
    #pragma unroll
    for (int ks = 0; ks < 4; ++ks) {
        d[0][ks] = *(const short8*)(p0 + off + ks * 32 + ao);
        d[1][ks] = *(const short8*)(p1 + off + ks * 32 + ao);
    }
}
__device__ __forceinline__ void convHalf(float4v (&acc)[2][8], const short8 (&a)[2][4],
                                         const ushort* bsm_h, int h, int lane) {
    #pragma unroll
    for (int nt4 = 0; nt4 < 4; ++nt4) {
        #pragma unroll
        for (int ks = 0; ks < 4; ++ks) {
            short8 b = *(const short8*)(bsm_h + (((nt4 * 4 + ks) * 64 + lane) << 3));
            acc[0][h * 4 + nt4] = __builtin_amdgcn_mfma_f32_16x16x32_bf16(
                a[0][ks], b, acc[0][h * 4 + nt4], 0, 0, 0);
            acc[1][h * 4 + nt4] = __builtin_amdgcn_mfma_f32_16x16x32_bf16(
                a[1][ks], b, acc[1][h * 4 + nt4], 0, 0, 0);
        }
    }
}
__device__ __forceinline__ void mlpHalf(float4v (&ct)[2][4], const short8 (&a2)[2][4],
                                        const ushort* bsm_h, int lane) {
    #pragma unroll
    for (int nt4 = 0; nt4 < 4; ++nt4) {
        #pragma unroll
        for (int ks = 0; ks < 4; ++ks) {
            short8 b = *(const short8*)(bsm_h + (((nt4 * 4 + ks) * 64 + lane) << 3));
            ct[0][nt4] = __builtin_amdgcn_mfma_f32_16x16x32_bf16(a2[0][ks], b, ct[0][nt4], 0, 0, 0);
            ct[1][nt4] = __builtin_amdgcn_mfma_f32_16x16x32_bf16(a2[1][ks], b, ct[1][nt4], 0, 0, 0);
        }
    }
}

__launch_bounds__(256, 2)
__global__ void k_gm(const ushort* __restrict__ ybuf, const ushort* __restrict__ zbuf,
                     const ushort* __restrict__ Wt, const float* __restrict__ x,
                     const int* __restrict__ ntp,
                     const float* __restrict__ gamma, const float* __restrict__ beta,
                     const float* __restrict__ bmlp, float* __restrict__ out, int N) {
    __shared__ ushort bsm[2][8192];      // 2 x 16KB half-mat ping-pong
    __shared__ ushort ysm[4][32][140];   // per-wave y2 tiles (35.8KB)
    ushort* bsm0 = &bsm[0][0];
    int tid = threadIdx.x;
    int wave = tid >> 6, lane = tid & 63;
    int quad = lane >> 4, l15 = lane & 15;
    int ao = quad * 8;
    int base = blockIdx.x * 128 + wave * 32;            // 32 rows per wave

    const ushort* yrow0 = ybuf + (size_t)min(base + l15,      N - 1) * 128;
    const ushort* yrow1 = ybuf + (size_t)min(base + 16 + l15, N - 1) * 128;
    const ushort* zrow0 = zbuf + (size_t)min(base + l15,      N - 1) * 1024;
    const ushort* zrow1 = zbuf + (size_t)min(base + 16 + l15, N - 1) * 1024;

    float4v acc[2][8];
    #pragma unroll
    for (int g = 0; g < 2; ++g)
        #pragma unroll
        for (int nt = 0; nt < 8; ++nt) acc[g][nt] = (float4v){0.f, 0.f, 0.f, 0.f};

    // ---- prologue: stage half 0, prefetch A[0] (ybuf) and A[1] (z slot 0) ----
    short8 aC[2][4], aN[2][4];
    stage_half(Wt, 0, bsm0, wave, lane);
    aload4(aC, yrow0, yrow1, 0, ao);
    aload4(aN, zrow0, zrow1, 0, ao);
    __syncthreads();

    // ---- conv: 18 half-mat phases, A prefetched ~2 mats ahead in regs ----
    #pragma unroll
    for (int m = 0; m < 9; ++m) {
        short8 (&cur)[2][4] = (m & 1) ? aN : aC;        // holds A[m]
        // even phase 2m: stage half 2m+1 -> bsm[1]; compute h0 from bsm[0]
        stage_half(Wt, 2 * m + 1, bsm0, wave, lane);
        convHalf(acc, cur, bsm0, 0, lane);
        __syncthreads();
        // odd phase 2m+1: stage half 2m+2 -> bsm[0]; compute h1 from bsm[1]
        // (LAST use of cur); THEN prefetch A[m+2] into cur.
        stage_half(Wt, 2 * m + 2, bsm0, wave, lane);
        convHalf(acc, cur, bsm0 + 8192, 1, lane);
        if (m < 7) aload4(cur, zrow0, zrow1, (m + 1) * 128, ao);
        __syncthreads();
    }

    // ---- epilogue: x2 = x + acc (kept in acc); LN2 + ReLU -> y2 tile ----
    int ty[2][4];
    #pragma unroll
    for (int g = 0; g < 2; ++g) {
        int gb = base + g * 16;
        float s[4] = {0.f, 0.f, 0.f, 0.f}, s2[4] = {0.f, 0.f, 0.f, 0.f};
        #pragma unroll
        for (int nt = 0; nt < 8; ++nt) {
            int col = nt * 16 + l15;
            #pragma unroll
            for (int r = 0; r < 4; ++r) {
                int row = gb + quad * 4 + r;
                float xv = (row < N) ? x[(size_t)row * D + col] : 0.f;
                float t = acc[g][nt][r] + xv;
                acc[g][nt][r] = t;
                s[r] += t; s2[r] += t * t;
            }
        }
        #pragma unroll
        for (int r = 0; r < 4; ++r) {
            #pragma unroll
            for (int o = 1; o < 16; o <<= 1) {
                s[r]  += __shfl_xor(s[r],  o, 64);
                s2[r] += __shfl_xor(s2[r], o, 64);
            }
        }
        #pragma unroll
        for (int r = 0; r < 4; ++r) {
            int rc = min(gb + quad * 4 + r, N - 1);
            ty[g][r] = ntp[rc];
            float mu  = s[r] * (1.0f / D);
            float var = s2[r] * (1.0f / D) - mu * mu;
            float inv = rsqrtf(var + EPS);
            int lrow = g * 16 + quad * 4 + r;
            #pragma unroll
            for (int nt = 0; nt < 8; ++nt) {
                int col = nt * 16 + l15;
                float yn = fmaxf((acc[g][nt][r] - mu) * inv * gamma[ty[g][r] * D + col]
                                 + beta[ty[g][r] * D + col], 0.f);
                ysm[wave][lrow][col] = f2bf(yn);
            }
        }
    }
    // MLP A-fragments: intra-wave LDS read-back (own rows only)
    short8 a2[2][4];
    #pragma unroll
    for (int g = 0; g < 2; ++g) {
        const ushort* myrow = &ysm[wave][g * 16 + l15][0];
        #pragma unroll
        for (int ks = 0; ks < 4; ++ks) a2[g][ks] = *(const short8*)(myrow + ks * 32 + ao);
    }

    // ---- MLP: 8 staged half phases (mats 9..12), per-tm compute + select ----
    // (conv's last phase pre-staged half 18 = mat 9 half 0 into bsm[0])
    float4v oSel[2][8];
    #pragma unroll
    for (int g = 0; g < 2; ++g)
        #pragma unroll
        for (int nt = 0; nt < 8; ++nt) oSel[g][nt] = (float4v){0.f, 0.f, 0.f, 0.f};

    #pragma unroll
    for (int tm = 0; tm < 4; ++tm) {
        // hh=0: stage next half -> bsm[1]; compute nt 0..3 of mat 9+tm from bsm[0]
        stage_half(Wt, 19 + 2 * tm, bsm0, wave, lane);
        {
            float4v ct[2][4];
            #pragma unroll
            for (int g = 0; g < 2; ++g)
                #pragma unroll
                for (int n4 = 0; n4 < 4; ++n4) ct[g][n4] = (float4v){0.f, 0.f, 0.f, 0.f};
            mlpHalf(ct, a2, bsm0, lane);
            #pragma unroll
            for (int g = 0; g < 2; ++g)
                #pragma unroll
                for (int n4 = 0; n4 < 4; ++n4)
                    #pragma unroll
                    for (int r = 0; r < 4; ++r)
                        if (ty[g][r] == tm) oSel[g][n4][r] = ct[g][n4][r];
        }
        __syncthreads();
        // hh=1: stage next tm's half0 -> bsm[0]; compute nt 4..7 from bsm[1]
        if (tm < 3) stage_half(Wt, 20 + 2 * tm, bsm0, wave, lane);
        {
            float4v ct[2][4];
            #pragma unroll
            for (int g = 0; g < 2; ++g)
                #pragma unroll
                for (int n4 = 0; n4 < 4; ++n4) ct[g][n4] = (float4v){0.f, 0.f, 0.f, 0.f};
            mlpHalf(ct, a2, bsm0 + 8192, lane);
            #pragma unroll
            for (int g = 0; g < 2; ++g)
                #pragma unroll
                for (int n4 = 0; n4 < 4; ++n4)
                    #pragma unroll
                    for (int r = 0; r < 4; ++r)
                        if (ty[g][r] == tm) oSel[g][4 + n4][r] = ct[g][n4][r];
        }
        if (tm < 3) __syncthreads();
    }

    // ---- final store: out = x2 + mlp + bias ----
    #pragma unroll
    for (int nt = 0; nt < 8; ++nt) {
        int col = nt * 16 + l15;
        #pragma unroll
        for (int g = 0; g < 2; ++g) {
            #pragma unroll
            for (int r = 0; r < 4; ++r) {
                int row = base + g * 16 + quad * 4 + r;
                if (row < N) {
                    int t = ty[g][r];
                    out[(size_t)row * D + col] =
                        acc[g][nt][r] + oSel[g][nt][r] + bmlp[t * D + col];
                }
            }
        }
    }
}

// ---------- launch ------------------------------------------------------------
extern "C" void kernel_launch(void* const* d_in, const int* in_sizes, int n_in,
                              void* d_out, int out_size, void* d_ws, size_t ws_size,
                              hipStream_t stream) {
    const float* x          = (const float*)d_in[0];
    const int*   esrc       = (const int*)d_in[1];
    const int*   edst       = (const int*)d_in[2];
    const int*   ntyp       = (const int*)d_in[3];
    const int*   etyp       = (const int*)d_in[4];
    const float* conv_gamma = (const float*)d_in[5];
    const float* conv_beta  = (const float*)d_in[6];
    const float* W_rel      = (const float*)d_in[7];
    const float* W_root     = (const float*)d_in[8];
    const float* mlp_gamma  = (const float*)d_in[9];
    const float* mlp_beta   = (const float*)d_in[10];
    const float* W_mlp      = (const float*)d_in[11];
    const float* b_mlp      = (const float*)d_in[12];
    float* out = (float*)d_out;

    int N = in_sizes[0] / D;
    int E = in_sizes[1];
    int C = (E + CHK - 1) / CHK;        // chunks (<=128)
    int B = (N + 255) / 256;            // coarse buckets (<=256)

    char* p = (char*)d_ws;
    auto take = [&p](size_t bytes) { char* q = p; p += (bytes + 255) & ~(size_t)255; return q; };
    ushort* ybuf    = (ushort*)take((size_t)N * D * 2);
    ushort* zbuf    = (ushort*)take((size_t)N * 1024 * 2);
    ushort* Wt      = (ushort*)take((size_t)13 * D * D * 2);
    uint*   edata   = (uint*)take((size_t)E * 4);
    uint*   epack   = (uint*)take((size_t)E * 4);
    int*    offs    = (int*)take((size_t)(N + 1) * 4);
    int*    hist    = (int*)take((size_t)C * B * 4);
    int*    chunkoff= (int*)take((size_t)C * B * 4);
    int*    bucktot = (int*)take((size_t)B * 4);

    k_ln1cvt<<<13 + (N + 3) / 4, 256, 0, stream>>>(x, ntyp, conv_gamma, conv_beta,
                                                   ybuf, W_rel, W_root, W_mlp, Wt, N);

    k_c1<<<C, 256, 0, stream>>>(edst, hist, E, B);
    k_c2<<<B, 128, 0, stream>>>(hist, chunkoff, bucktot, C, B);
    k_p1s<<<C, 256, 0, stream>>>(edst, esrc, etyp, bucktot, chunkoff, edata, E, B);
    k_p2<<<B, 256, 0, stream>>>(edata, bucktot, epack, offs, N, E, B);

    k_zagg<<<(N + 3) / 4, 256, 0, stream>>>(ybuf, offs, epack, zbuf, N);

    k_gm<<<(N + 127) / 128, 256, 0, stream>>>(ybuf, zbuf, Wt, x, ntyp,
                                              mlp_gamma, mlp_beta, b_mlp, out, N);
}

// Round 6
// 275.295 us; speedup vs baseline: 1.2609x; 1.2609x over previous
//
#include <hip/hip_runtime.h>
#include <hip/hip_bf16.h>

#define D 128
#define EPS 1e-5f
#define CHK 8192            // edges per phase-1 chunk
#define P2CAP 6144          // max edges per 256-dst bucket

typedef __attribute__((ext_vector_type(8))) short short8;
typedef __attribute__((ext_vector_type(4))) float float4v;

#define AS1 __attribute__((address_space(1)))
#define AS3 __attribute__((address_space(3)))

__device__ inline ushort f2bf(float f) {
    __hip_bfloat16 b = __float2bfloat16(f);
    return *reinterpret_cast<ushort*>(&b);
}
__device__ inline float bf_lo(uint u) { return __uint_as_float(u << 16); }
__device__ inline float bf_hi(uint u) { return __uint_as_float(u & 0xffff0000u); }

// ---------- K1: fused weight-convert (blocks 0..12) + LN1+ReLU (rest) ---------
// cvt: m==0 W_root, 1..8 W_rel[m-1], 9..12 W_mlp[m-9] -> bf16 B-fragment order.
__global__ void k_ln1cvt(const float* __restrict__ x, const int* __restrict__ ntp,
                         const float* __restrict__ gamma, const float* __restrict__ beta,
                         ushort* __restrict__ y,
                         const float* __restrict__ Wrel, const float* __restrict__ Wroot,
                         const float* __restrict__ Wmlp, ushort* __restrict__ Wt, int N) {
    __shared__ ushort t[128][136];
    if (blockIdx.x < 13) {
        int m = blockIdx.x;
        const float* src = (m == 0) ? Wroot
                         : (m <= 8) ? Wrel + (size_t)(m - 1) * D * D
                                    : Wmlp + (size_t)(m - 9) * D * D;
        for (int i = threadIdx.x; i < D * D; i += 256) {
            int k = i >> 7, n = i & 127;
            t[n][k] = f2bf(src[i]);
        }
        __syncthreads();
        ushort* dst = Wt + (size_t)m * D * D;
        for (int i = threadIdx.x; i < D * D; i += 256) {
            int frag = i >> 9;
            int lane = (i >> 3) & 63;
            int j = i & 7;
            int nt = frag >> 2, ks = frag & 3;
            int n = nt * 16 + (lane & 15);
            int k = ks * 32 + (lane >> 4) * 8 + j;
            dst[i] = t[n][k];
        }
        return;
    }
    int n = (blockIdx.x - 13) * 4 + (threadIdx.x >> 6);
    if (n >= N) return;
    int l = threadIdx.x & 63;
    float2 v = *(const float2*)(x + (size_t)n * D + 2 * l);
    float s = v.x + v.y, s2 = v.x * v.x + v.y * v.y;
    #pragma unroll
    for (int o = 32; o; o >>= 1) { s += __shfl_xor(s, o, 64); s2 += __shfl_xor(s2, o, 64); }
    float mu = s * (1.0f / D);
    float var = s2 * (1.0f / D) - mu * mu;
    float inv = rsqrtf(var + EPS);
    int tt = ntp[n];
    float2 g = *(const float2*)(gamma + tt * D + 2 * l);
    float2 b = *(const float2*)(beta + tt * D + 2 * l);
    float a0 = fmaxf((v.x - mu) * inv * g.x + b.x, 0.0f);
    float a1 = fmaxf((v.y - mu) * inv * g.y + b.y, 0.0f);
    ((uint*)(y + (size_t)n * D))[l] = ((uint)f2bf(a1) << 16) | f2bf(a0);
}

// ---------- two-phase edge sort by dst (block-owned write regions) ------------
__global__ void k_c1(const int* __restrict__ edst, int* __restrict__ hist, int E, int B) {
    __shared__ int cnt[256];
    int c = blockIdx.x, tid = threadIdx.x;
    cnt[tid] = 0;
    __syncthreads();
    #pragma unroll 4
    for (int k = 0; k < CHK / 256; ++k) {
        int e = c * CHK + k * 256 + tid;
        if (e < E) atomicAdd(&cnt[edst[e] >> 8], 1);
    }
    __syncthreads();
    if (tid < B) hist[c * B + tid] = cnt[tid];
}
__global__ void k_c2(const int* __restrict__ hist, int* __restrict__ chunkoff,
                     int* __restrict__ bucktot, int C, int B) {
    __shared__ int v[128];
    int b = blockIdx.x, t = threadIdx.x;
    v[t] = (t < C) ? hist[t * B + b] : 0;
    __syncthreads();
    if (t == 0) {
        int s = 0;
        for (int c = 0; c < C; ++c) { int x = v[c]; v[c] = s; s += x; }
        bucktot[b] = s;
    }
    __syncthreads();
    if (t < C) chunkoff[t * B + b] = v[t];
}
// p1s: scatter edges into bucket-major edata; in-block scan of bucktot -> base
__global__ void k_p1s(const int* __restrict__ edst, const int* __restrict__ esrc,
                      const int* __restrict__ etyp, const int* __restrict__ bucktot,
                      const int* __restrict__ chunkoff, uint* __restrict__ edata,
                      int E, int B) {
    __shared__ int ps[256];
    __shared__ int base[256];
    __shared__ int cnt[256];
    int c = blockIdx.x, tid = threadIdx.x;
    int bt = (tid < B) ? bucktot[tid] : 0;
    ps[tid] = bt;
    __syncthreads();
    for (int o = 1; o < 256; o <<= 1) {
        int v = (tid >= o) ? ps[tid - o] : 0;
        __syncthreads();
        ps[tid] += v;
        __syncthreads();
    }
    base[tid] = (ps[tid] - bt) + ((tid < B) ? chunkoff[c * B + tid] : 0);
    cnt[tid] = 0;
    __syncthreads();
    #pragma unroll 4
    for (int k = 0; k < CHK / 256; ++k) {
        int e = c * CHK + k * 256 + tid;
        if (e < E) {
            int d = edst[e];
            int b = d >> 8;
            int r = atomicAdd(&cnt[b], 1);
            edata[base[b] + r] =
                ((uint)esrc[e] << 12) | ((uint)(d & 255) << 4) | (uint)etyp[e];
        }
    }
}
// p2: exact counting-sort within each 256-dst bucket; in-block scan for j0
__global__ void k_p2(const uint* __restrict__ edata, const int* __restrict__ bucktot,
                     uint* __restrict__ epack, int* __restrict__ offs,
                     int N, int E, int B) {
    __shared__ int ps[256];
    __shared__ uint ed[P2CAP];
    __shared__ int cnt[256], off[256], cur[256];
    int b = blockIdx.x, tid = threadIdx.x;
    int bt = (tid < B) ? bucktot[tid] : 0;
    ps[tid] = bt;
    __syncthreads();
    for (int o = 1; o < 256; o <<= 1) {
        int v = (tid >= o) ? ps[tid - o] : 0;
        __syncthreads();
        ps[tid] += v;
        __syncthreads();
    }
    int j0 = ps[b] - ((b < B) ? bucktot[b] : 0);   // exclusive prefix of bucket b
    int count = ps[b] - j0;
    if (count > P2CAP) count = P2CAP;
    for (int i = tid; i < count; i += 256) ed[i] = edata[j0 + i];
    cnt[tid] = 0;
    __syncthreads();
    for (int i = tid; i < count; i += 256) atomicAdd(&cnt[(ed[i] >> 4) & 255], 1);
    __syncthreads();
    if (tid == 0) {
        int s = 0;
        for (int i = 0; i < 256; ++i) { off[i] = s; cur[i] = s; s += cnt[i]; }
    }
    __syncthreads();
    for (int i = tid; i < count; i += 256) {
        uint v = ed[i];
        int dl = (v >> 4) & 255;
        int r = atomicAdd(&cur[dl], 1);
        epack[j0 + r] = ((v & 15u) << 28) | (v >> 12);
    }
    int v = b * 256 + tid;
    if (v < N) offs[v] = j0 + off[tid];
    if (b == 0 && tid == 0) offs[N] = E;
}

// ---------- K3: z[v][r] = sum of y[src] over edges (dst=v, type=r) ------------
__global__ void k_zagg(const ushort* __restrict__ ybuf, const int* __restrict__ offs,
                       const uint* __restrict__ epack, ushort* __restrict__ zbuf, int N) {
    int wave = threadIdx.x >> 6;
    int l = threadIdx.x & 63;
    int v = blockIdx.x * 4 + wave;
    if (v >= N) return;
    float2 a0 = {0.f,0.f}, a1 = {0.f,0.f}, a2 = {0.f,0.f}, a3 = {0.f,0.f};
    float2 a4 = {0.f,0.f}, a5 = {0.f,0.f}, a6 = {0.f,0.f}, a7 = {0.f,0.f};
    const uint* yb = (const uint*)ybuf;
    int j = offs[v], e1 = offs[v + 1];

#define ZACC(P, U) do {                                                   \
        float lo = bf_lo(U), hi = bf_hi(U);                               \
        switch ((P) >> 28) {                                              \
            case 0: a0.x += lo; a0.y += hi; break;                        \
            case 1: a1.x += lo; a1.y += hi; break;                        \
            case 2: a2.x += lo; a2.y += hi; break;                        \
            case 3: a3.x += lo; a3.y += hi; break;                        \
            case 4: a4.x += lo; a4.y += hi; break;                        \
            case 5: a5.x += lo; a5.y += hi; break;                        \
            case 6: a6.x += lo; a6.y += hi; break;                        \
            default: a7.x += lo; a7.y += hi; break;                       \
        }                                                                 \
    } while (0)

    while (j < e1) {
        int chunk = min(64, e1 - j);
        uint pl = (j + l < e1) ? epack[j + l] : 0;
        int i = 0;
        for (; i + 3 < chunk; i += 4) {
            uint p0 = __shfl(pl, i, 64);
            uint p1 = __shfl(pl, i + 1, 64);
            uint p2 = __shfl(pl, i + 2, 64);
            uint p3 = __shfl(pl, i + 3, 64);
            uint u0 = yb[(size_t)(p0 & 0x0FFFFFFFu) * 64 + l];
            uint u1 = yb[(size_t)(p1 & 0x0FFFFFFFu) * 64 + l];
            uint u2 = yb[(size_t)(p2 & 0x0FFFFFFFu) * 64 + l];
            uint u3 = yb[(size_t)(p3 & 0x0FFFFFFFu) * 64 + l];
            ZACC(p0, u0); ZACC(p1, u1); ZACC(p2, u2); ZACC(p3, u3);
        }
        for (; i < chunk; ++i) {
            uint p = __shfl(pl, i, 64);
            uint u = yb[(size_t)(p & 0x0FFFFFFFu) * 64 + l];
            ZACC(p, u);
        }
        j += chunk;
    }
#undef ZACC
    uint* zrow = (uint*)(zbuf + (size_t)v * 1024);
    zrow[0 * 64 + l] = ((uint)f2bf(a0.y) << 16) | f2bf(a0.x);
    zrow[1 * 64 + l] = ((uint)f2bf(a1.y) << 16) | f2bf(a1.x);
    zrow[2 * 64 + l] = ((uint)f2bf(a2.y) << 16) | f2bf(a2.x);
    zrow[3 * 64 + l] = ((uint)f2bf(a3.y) << 16) | f2bf(a3.x);
    zrow[4 * 64 + l] = ((uint)f2bf(a4.y) << 16) | f2bf(a4.x);
    zrow[5 * 64 + l] = ((uint)f2bf(a5.y) << 16) | f2bf(a5.x);
    zrow[6 * 64 + l] = ((uint)f2bf(a6.y) << 16) | f2bf(a6.x);
    zrow[7 * 64 + l] = ((uint)f2bf(a7.y) << 16) | f2bf(a7.x);
}

// ---------- K4: LDS-staged conv-GEMM (K=1152) + LN2 + ReLU + MLP --------------
// R6: register-pressure fix. R5 passed but spilled (WRITE_SIZE 124MB vs 25MB
// out): acc[2][8]+aC/aN held 128+ VGPRs vs the allocator's 128 budget.
//  - wave tile 32 -> 16 rows: acc=32, aC/aN=16 each, a2=16 held.
//  - MLP: no oSel accumulator. Weights staged per-nt SLICE across all 4 types
//    (16KB = 4 x 4KB chunks, wave w stages type w); each phase computes
//    c0..c3 (transient), selects by node type, stores out immediately.
// Peak live ~100 VGPR -> fits 128, zero spill. Sync stays __syncthreads().
__device__ __forceinline__ void gl_lds16(const void* g, void* l) {
    __builtin_amdgcn_global_load_lds((const AS1 void*)g, (AS3 void*)l, 16, 0, 0);
}
// stage 16KB half q (Wt bytes [q*16384, +16384)) into bsm[q&1]; 4KB per wave
__device__ __forceinline__ void stage_half(const ushort* __restrict__ Wt, int q,
                                           ushort* bsm0, int wave, int lane) {
    const char* g = (const char*)Wt + (size_t)q * 16384 + lane * 16;
    char* l = (char*)bsm0 + (q & 1) * 16384;
    #pragma unroll
    for (int i = 0; i < 4; ++i) {
        int c = i * 4 + wave;
        gl_lds16(g + c * 1024, l + c * 1024);
    }
}
// stage MLP slice nt (4 types x 4KB) into bsm[nt&1]; wave w stages type w
__device__ __forceinline__ void stage_mlp_slice(const ushort* __restrict__ Wt, int nt,
                                                ushort* bsm0, int wave, int lane) {
    const char* g = (const char*)Wt + (size_t)(9 + wave) * 32768 + nt * 4096 + lane * 16;
    char* l = (char*)bsm0 + (nt & 1) * 16384 + wave * 4096;
    #pragma unroll
    for (int i = 0; i < 4; ++i)
        gl_lds16(g + i * 1024, l + i * 1024);
}
__device__ __forceinline__ void aloadG(short8 (&d)[4], const ushort* p, int off, int ao) {
    #pragma unroll
    for (int ks = 0; ks < 4; ++ks)
        d[ks] = *(const short8*)(p + off + ks * 32 + ao);
}
__device__ __forceinline__ void convHalf(float4v (&acc)[8], const short8 (&a)[4],
                                         const ushort* bsm_h, int h, int lane) {
    #pragma unroll
    for (int nt4 = 0; nt4 < 4; ++nt4) {
        #pragma unroll
        for (int ks = 0; ks < 4; ++ks) {
            short8 b = *(const short8*)(bsm_h + (((nt4 * 4 + ks) * 64 + lane) << 3));
            acc[h * 4 + nt4] = __builtin_amdgcn_mfma_f32_16x16x32_bf16(
                a[ks], b, acc[h * 4 + nt4], 0, 0, 0);
        }
    }
}

__launch_bounds__(256, 2)
__global__ void k_gm(const ushort* __restrict__ ybuf, const ushort* __restrict__ zbuf,
                     const ushort* __restrict__ Wt, const float* __restrict__ x,
                     const int* __restrict__ ntp,
                     const float* __restrict__ gamma, const float* __restrict__ beta,
                     const float* __restrict__ bmlp, float* __restrict__ out, int N) {
    __shared__ ushort bsm[2][8192];      // 2 x 16KB ping-pong
    __shared__ ushort ysm[4][16][140];   // per-wave y2 tiles (17.9KB)
    ushort* bsm0 = &bsm[0][0];
    int tid = threadIdx.x;
    int wave = tid >> 6, lane = tid & 63;
    int quad = lane >> 4, l15 = lane & 15;
    int ao = quad * 8;
    int base = blockIdx.x * 64 + wave * 16;             // 16 rows per wave

    const ushort* yrow = ybuf + (size_t)min(base + l15, N - 1) * 128;
    const ushort* zrow = zbuf + (size_t)min(base + l15, N - 1) * 1024;

    float4v acc[8];
    #pragma unroll
    for (int nt = 0; nt < 8; ++nt) acc[nt] = (float4v){0.f, 0.f, 0.f, 0.f};

    // ---- prologue: stage half 0; A[0] (ybuf) ----
    short8 aC[4], aN[4];
    stage_half(Wt, 0, bsm0, wave, lane);
    aloadG(aC, yrow, 0, ao);
    __syncthreads();

    // ---- conv: 18 half-mat phases; A[m+1] loaded during even phase of mat m ----
    #pragma unroll
    for (int m = 0; m < 9; ++m) {
        short8 (&cur)[4] = (m & 1) ? aN : aC;           // holds A[m]
        short8 (&nxt)[4] = (m & 1) ? aC : aN;
        // even phase 2m: stage half 2m+1 -> bsm[1]; prefetch A[m+1]; compute h0
        stage_half(Wt, 2 * m + 1, bsm0, wave, lane);
        if (m < 8) aloadG(nxt, zrow, m * 128, ao);      // A[m+1] = z slot m
        convHalf(acc, cur, bsm0, 0, lane);
        __syncthreads();
        // odd phase 2m+1: stage half 2m+2 (or MLP slice 0); compute h1
        if (m < 8) stage_half(Wt, 2 * m + 2, bsm0, wave, lane);
        else       stage_mlp_slice(Wt, 0, bsm0, wave, lane);
        convHalf(acc, cur, bsm0 + 8192, 1, lane);
        __syncthreads();
    }

    // ---- epilogue: x2 = x + acc (kept in acc); LN2 + ReLU -> y2 tile ----
    int ty[4];
    {
        float s[4] = {0.f, 0.f, 0.f, 0.f}, s2[4] = {0.f, 0.f, 0.f, 0.f};
        #pragma unroll
        for (int nt = 0; nt < 8; ++nt) {
            int col = nt * 16 + l15;
            #pragma unroll
            for (int r = 0; r < 4; ++r) {
                int row = base + quad * 4 + r;
                float xv = (row < N) ? x[(size_t)row * D + col] : 0.f;
                float t = acc[nt][r] + xv;
                acc[nt][r] = t;
                s[r] += t; s2[r] += t * t;
            }
        }
        #pragma unroll
        for (int r = 0; r < 4; ++r) {
            #pragma unroll
            for (int o = 1; o < 16; o <<= 1) {
                s[r]  += __shfl_xor(s[r],  o, 64);
                s2[r] += __shfl_xor(s2[r], o, 64);
            }
        }
        #pragma unroll
        for (int r = 0; r < 4; ++r) {
            int rc = min(base + quad * 4 + r, N - 1);
            ty[r] = ntp[rc];
            float mu  = s[r] * (1.0f / D);
            float var = s2[r] * (1.0f / D) - mu * mu;
            float inv = rsqrtf(var + EPS);
            int lrow = quad * 4 + r;
            #pragma unroll
            for (int nt = 0; nt < 8; ++nt) {
                int col = nt * 16 + l15;
                float yn = fmaxf((acc[nt][r] - mu) * inv * gamma[ty[r] * D + col]
                                 + beta[ty[r] * D + col], 0.f);
                ysm[wave][lrow][col] = f2bf(yn);
            }
        }
    }
    // MLP A-fragments: intra-wave LDS read-back (own rows only)
    short8 a2[4];
    {
        const ushort* myrow = &ysm[wave][l15][0];
        #pragma unroll
        for (int ks = 0; ks < 4; ++ks) a2[ks] = *(const short8*)(myrow + ks * 32 + ao);
    }

    // ---- MLP: 8 per-nt slice phases; compute 4 types, select, store out ----
    // (conv's last phase pre-staged slice 0 into bsm[0])
    #pragma unroll
    for (int nt = 0; nt < 8; ++nt) {
        if (nt < 7) stage_mlp_slice(Wt, nt + 1, bsm0, wave, lane);
        const ushort* bh = bsm0 + (nt & 1) * 8192;
        float4v c0 = {0.f,0.f,0.f,0.f}, c1 = {0.f,0.f,0.f,0.f};
        float4v c2 = {0.f,0.f,0.f,0.f}, c3 = {0.f,0.f,0.f,0.f};
        #pragma unroll
        for (int ks = 0; ks < 4; ++ks) {
            int fo = (ks * 64 + lane) << 3;
            short8 b0 = *(const short8*)(bh + 0 * 2048 + fo);
            short8 b1 = *(const short8*)(bh + 1 * 2048 + fo);
            short8 b2 = *(const short8*)(bh + 2 * 2048 + fo);
            short8 b3 = *(const short8*)(bh + 3 * 2048 + fo);
            c0 = __builtin_amdgcn_mfma_f32_16x16x32_bf16(a2[ks], b0, c0, 0, 0, 0);
            c1 = __builtin_amdgcn_mfma_f32_16x16x32_bf16(a2[ks], b1, c1, 0, 0, 0);
            c2 = __builtin_amdgcn_mfma_f32_16x16x32_bf16(a2[ks], b2, c2, 0, 0, 0);
            c3 = __builtin_amdgcn_mfma_f32_16x16x32_bf16(a2[ks], b3, c3, 0, 0, 0);
        }
        int col = nt * 16 + l15;
        #pragma unroll
        for (int r = 0; r < 4; ++r) {
            int row = base + quad * 4 + r;
            if (row < N) {
                int t = ty[r];
                float v = (t == 0) ? c0[r] : (t == 1) ? c1[r] : (t == 2) ? c2[r] : c3[r];
                out[(size_t)row * D + col] = acc[nt][r] + v + bmlp[t * D + col];
            }
        }
        if (nt < 7) __syncthreads();
    }
}

// ---------- launch ------------------------------------------------------------
extern "C" void kernel_launch(void* const* d_in, const int* in_sizes, int n_in,
                              void* d_out, int out_size, void* d_ws, size_t ws_size,
                              hipStream_t stream) {
    const float* x          = (const float*)d_in[0];
    const int*   esrc       = (const int*)d_in[1];
    const int*   edst       = (const int*)d_in[2];
    const int*   ntyp       = (const int*)d_in[3];
    const int*   etyp       = (const int*)d_in[4];
    const float* conv_gamma = (const float*)d_in[5];
    const float* conv_beta  = (const float*)d_in[6];
    const float* W_rel      = (const float*)d_in[7];
    const float* W_root     = (const float*)d_in[8];
    const float* mlp_gamma  = (const float*)d_in[9];
    const float* mlp_beta   = (const float*)d_in[10];
    const float* W_mlp      = (const float*)d_in[11];
    const float* b_mlp      = (const float*)d_in[12];
    float* out = (float*)d_out;

    int N = in_sizes[0] / D;
    int E = in_sizes[1];
    int C = (E + CHK - 1) / CHK;        // chunks (<=128)
    int B = (N + 255) / 256;            // coarse buckets (<=256)

    char* p = (char*)d_ws;
    auto take = [&p](size_t bytes) { char* q = p; p += (bytes + 255) & ~(size_t)255; return q; };
    ushort* ybuf    = (ushort*)take((size_t)N * D * 2);
    ushort* zbuf    = (ushort*)take((size_t)N * 1024 * 2);
    ushort* Wt      = (ushort*)take((size_t)13 * D * D * 2);
    uint*   edata   = (uint*)take((size_t)E * 4);
    uint*   epack   = (uint*)take((size_t)E * 4);
    int*    offs    = (int*)take((size_t)(N + 1) * 4);
    int*    hist    = (int*)take((size_t)C * B * 4);
    int*    chunkoff= (int*)take((size_t)C * B * 4);
    int*    bucktot = (int*)take((size_t)B * 4);

    k_ln1cvt<<<13 + (N + 3) / 4, 256, 0, stream>>>(x, ntyp, conv_gamma, conv_beta,
                                                   ybuf, W_rel, W_root, W_mlp, Wt, N);

    k_c1<<<C, 256, 0, stream>>>(edst, hist, E, B);
    k_c2<<<B, 128, 0, stream>>>(hist, chunkoff, bucktot, C, B);
    k_p1s<<<C, 256, 0, stream>>>(edst, esrc, etyp, bucktot, chunkoff, edata, E, B);
    k_p2<<<B, 256, 0, stream>>>(edata, bucktot, epack, offs, N, E, B);

    k_zagg<<<(N + 3) / 4, 256, 0, stream>>>(ybuf, offs, epack, zbuf, N);

    k_gm<<<(N + 63) / 64, 256, 0, stream>>>(ybuf, zbuf, Wt, x, ntyp,
                                            mlp_gamma, mlp_beta, b_mlp, out, N);
}